// Round 1
// baseline (740.517 us; speedup 1.0000x reference)
//
#include <hip/hip_runtime.h>
#include <stdint.h>

namespace {

constexpr int BATCH = 16;
constexpr int LQ = 2048;
constexpr int LK = 2048;
constexpr int DIM = 64;
constexpr int QB = 64;      // q rows per block
constexpr int KB = 64;      // k cols per LDS tile
constexpr int BLOCK = 128;  // threads (2 waves)
constexpr int MSTRIDE = 68; // padded mask stride (ints) -> bank (4r+k)%32, 2-way max (free)

// Detect how the bool mask was pushed to device.
// int32 mask: words are 0 or 1. float32 mask: words are 0 or 0x3F800000.
// uint8 mask: words are 4 packed 0/1 bytes -> values like 0x00010001 appear
// with overwhelming probability in 4096 words. Both the {0,1} and
// {0,0x3F800000} cases are handled by the same "!=0" test at 4-byte width,
// so the only thing we must distinguish is byte width.
__global__ void detect_mask_dtype(const uint32_t* __restrict__ mask,
                                  int* __restrict__ flag) {
  __shared__ int bad;
  if (threadIdx.x == 0) bad = 0;
  __syncthreads();
  int my = 0;
  for (int i = threadIdx.x; i < 4096; i += 256) {
    uint32_t w = mask[i];
    if (w > 1u && w != 0x3F800000u) my = 1;
  }
  if (my) atomicOr(&bad, 1);
  __syncthreads();
  if (threadIdx.x == 0) *flag = bad;  // 1 -> mask is uint8-packed
}

__device__ inline float dot4(float4 a, float4 b) {
  return fmaf(a.x, b.x, fmaf(a.y, b.y, fmaf(a.z, b.z, a.w * b.w)));
}

__global__ __launch_bounds__(BLOCK) void attn_fp32(
    const float* __restrict__ qp, const float* __restrict__ kp,
    const float* __restrict__ vp, const uint32_t* __restrict__ maskp,
    const int* __restrict__ flagp, float* __restrict__ out) {
  __shared__ float4 Ks[KB * (DIM / 4)];
  __shared__ float4 Vs[KB * (DIM / 4)];
  __shared__ int Ms[QB][MSTRIDE];

  const int tid = threadIdx.x;
  const int quad = tid & 3;   // which 16-dim slice of d
  const int g = tid >> 2;     // row group 0..31
  const int bid = blockIdx.x;
  const int b = bid >> 5;     // 32 q-tiles per batch
  const int qt = bid & 31;
  const int qbase = qt * QB;
  const int r0 = g;
  const int r1 = g + 32;
  const int isU8 = *flagp;

  // Q fragments in registers: 2 rows x 16 dims each
  float4 q0v[4], q1v[4];
  {
    const float4* qg0 = reinterpret_cast<const float4*>(
        qp + ((size_t)(b * LQ + qbase + r0)) * DIM + quad * 16);
    const float4* qg1 = reinterpret_cast<const float4*>(
        qp + ((size_t)(b * LQ + qbase + r1)) * DIM + quad * 16);
#pragma unroll
    for (int t = 0; t < 4; ++t) {
      q0v[t] = qg0[t];
      q1v[t] = qg1[t];
    }
  }

  float4 acc0[4], acc1[4];
#pragma unroll
  for (int t = 0; t < 4; ++t) {
    acc0[t] = make_float4(0.f, 0.f, 0.f, 0.f);
    acc1[t] = make_float4(0.f, 0.f, 0.f, 0.f);
  }
  float den0 = 0.f, den1 = 0.f;

  for (int kt = 0; kt < LK / KB; ++kt) {
    const int kbase = kt * KB;
    __syncthreads();
    // ---- stage K, V tiles (coalesced float4) ----
    {
      const float4* kg = reinterpret_cast<const float4*>(
          kp + ((size_t)(b * LK + kbase)) * DIM);
      const float4* vg = reinterpret_cast<const float4*>(
          vp + ((size_t)(b * LK + kbase)) * DIM);
#pragma unroll
      for (int i = 0; i < (KB * DIM / 4) / BLOCK; ++i) {  // 8
        Ks[tid + i * BLOCK] = kg[tid + i * BLOCK];
        Vs[tid + i * BLOCK] = vg[tid + i * BLOCK];
      }
    }
    // ---- stage mask tile ----
    if (!isU8) {
#pragma unroll
      for (int i = 0; i < (QB * KB / 4) / BLOCK; ++i) {  // 8
        int idx = tid + i * BLOCK;
        int r = idx >> 4;  // 16 int4 per row
        int c4 = idx & 15;
        const int4* mrow = reinterpret_cast<const int4*>(
            maskp + ((size_t)(b * LQ + qbase + r)) * LK + kbase);
        int4 m = mrow[c4];
        Ms[r][c4 * 4 + 0] = m.x;
        Ms[r][c4 * 4 + 1] = m.y;
        Ms[r][c4 * 4 + 2] = m.z;
        Ms[r][c4 * 4 + 3] = m.w;
      }
    } else {
      const uint8_t* m8 = reinterpret_cast<const uint8_t*>(maskp);
#pragma unroll
      for (int i = 0; i < (QB * KB / 4) / BLOCK; ++i) {  // 8
        int idx = tid + i * BLOCK;
        int r = idx >> 4;  // 16 uint32 (=64 bytes) per row
        int c = idx & 15;
        const uint32_t* mrow = reinterpret_cast<const uint32_t*>(
            m8 + ((size_t)(b * LQ + qbase + r)) * LK + kbase);
        uint32_t w = mrow[c];
        Ms[r][c * 4 + 0] = (int)(w & 0xFFu);
        Ms[r][c * 4 + 1] = (int)((w >> 8) & 0xFFu);
        Ms[r][c * 4 + 2] = (int)((w >> 16) & 0xFFu);
        Ms[r][c * 4 + 3] = (int)((w >> 24) & 0xFFu);
      }
    }
    __syncthreads();
    // ---- compute over this K/V tile ----
#pragma unroll 4
    for (int kk = 0; kk < KB; ++kk) {
      float4 kv[4];
#pragma unroll
      for (int t = 0; t < 4; ++t) kv[t] = Ks[kk * 16 + quad * 4 + t];
      float p0 = dot4(q0v[0], kv[0]) + dot4(q0v[1], kv[1]) +
                 dot4(q0v[2], kv[2]) + dot4(q0v[3], kv[3]);
      float p1 = dot4(q1v[0], kv[0]) + dot4(q1v[1], kv[1]) +
                 dot4(q1v[2], kv[2]) + dot4(q1v[3], kv[3]);
      // butterfly over the 4-lane quad -> full 64-dim dot in every lane
      p0 += __shfl_xor(p0, 1);
      p0 += __shfl_xor(p0, 2);
      p1 += __shfl_xor(p1, 1);
      p1 += __shfl_xor(p1, 2);
      // masked slots: score := 0 before exp -> weight exp(0) = 1
      float e0 = Ms[r0][kk] ? 1.0f : __expf(p0 * 0.125f);
      float e1 = Ms[r1][kk] ? 1.0f : __expf(p1 * 0.125f);
      den0 += e0;
      den1 += e1;
      float4 vv[4];
#pragma unroll
      for (int t = 0; t < 4; ++t) vv[t] = Vs[kk * 16 + quad * 4 + t];
#pragma unroll
      for (int t = 0; t < 4; ++t) {
        acc0[t].x = fmaf(e0, vv[t].x, acc0[t].x);
        acc0[t].y = fmaf(e0, vv[t].y, acc0[t].y);
        acc0[t].z = fmaf(e0, vv[t].z, acc0[t].z);
        acc0[t].w = fmaf(e0, vv[t].w, acc0[t].w);
        acc1[t].x = fmaf(e1, vv[t].x, acc1[t].x);
        acc1[t].y = fmaf(e1, vv[t].y, acc1[t].y);
        acc1[t].z = fmaf(e1, vv[t].z, acc1[t].z);
        acc1[t].w = fmaf(e1, vv[t].w, acc1[t].w);
      }
    }
  }

  const float inv0 = 1.0f / den0;
  const float inv1 = 1.0f / den1;
  float4* og0 = reinterpret_cast<float4*>(
      out + ((size_t)(b * LQ + qbase + r0)) * DIM + quad * 16);
  float4* og1 = reinterpret_cast<float4*>(
      out + ((size_t)(b * LQ + qbase + r1)) * DIM + quad * 16);
#pragma unroll
  for (int t = 0; t < 4; ++t) {
    og0[t] = make_float4(acc0[t].x * inv0, acc0[t].y * inv0, acc0[t].z * inv0,
                         acc0[t].w * inv0);
    og1[t] = make_float4(acc1[t].x * inv1, acc1[t].y * inv1, acc1[t].z * inv1,
                         acc1[t].w * inv1);
  }
}

}  // namespace

extern "C" void kernel_launch(void* const* d_in, const int* in_sizes, int n_in,
                              void* d_out, int out_size, void* d_ws,
                              size_t ws_size, hipStream_t stream) {
  const float* q = (const float*)d_in[0];
  const float* k = (const float*)d_in[1];
  const float* v = (const float*)d_in[2];
  const uint32_t* mask = (const uint32_t*)d_in[3];
  float* out = (float*)d_out;
  int* flag = (int*)d_ws;  // 4 bytes of scratch for the dtype flag

  detect_mask_dtype<<<1, 256, 0, stream>>>(mask, flag);
  attn_fp32<<<BATCH * (LQ / QB), BLOCK, 0, stream>>>(q, k, v, mask, flag, out);
}

// Round 3
// 166.264 us; speedup vs baseline: 4.4539x; 4.4539x over previous
//
#include <hip/hip_runtime.h>
#include <stdint.h>

namespace {

typedef short bf16x8 __attribute__((ext_vector_type(8)));
typedef float f32x4 __attribute__((ext_vector_type(4)));
typedef unsigned short u16x4 __attribute__((ext_vector_type(4)));

constexpr int BATCH = 16;
constexpr int LQ = 2048;
constexpr int LK = 2048;
constexpr int DIM = 64;
constexpr int QB = 64;   // q rows per block (4 waves x 16)
constexpr int KB = 64;   // k cols per tile
constexpr int NW = 4;    // waves per block
constexpr int BLOCK = 256;
constexpr float SCALE = 0.125f;  // 1/sqrt(64)

// Detect how the bool mask was pushed (4-byte {0,1}/{0,1.0f} vs packed u8).
__global__ void detect_mask_dtype(const uint32_t* __restrict__ mask,
                                  int* __restrict__ flag) {
  __shared__ int bad;
  if (threadIdx.x == 0) bad = 0;
  __syncthreads();
  int my = 0;
  for (int i = threadIdx.x; i < 4096; i += 256) {
    uint32_t w = mask[i];
    if (w > 1u && w != 0x3F800000u) my = 1;
  }
  if (my) atomicOr(&bad, 1);
  __syncthreads();
  if (threadIdx.x == 0) *flag = bad;  // 1 -> uint8-packed
}

__device__ inline unsigned short f2bf(float x) {  // RNE fp32->bf16
  union { float f; unsigned u; } c;
  c.f = x;
  unsigned r = c.u + 0x7FFFu + ((c.u >> 16) & 1u);
  return (unsigned short)(r >> 16);
}
__device__ inline float bf2f(unsigned short h) {
  union { float f; unsigned u; } c;
  c.u = (unsigned)h << 16;
  return c.f;
}

// mfma_f32_16x16x32_bf16 layouts (verified, guide §3 m89/m91 + m97 usage):
//   A: lane holds row m=l&15,  k=(l>>4)*8+e (8 contiguous bf16)
//   B: lane holds col n=l&15,  k=(l>>4)*8+e (8 contiguous bf16)
//   C/D: col n=l&15, row m=(l>>4)*4+reg

__global__ __launch_bounds__(BLOCK, 2) void attn_mfma(
    const float* __restrict__ qp, const float* __restrict__ kp,
    const float* __restrict__ vp, const uint32_t* __restrict__ maskp,
    const int* __restrict__ flagp, float* __restrict__ out) {
  // K stored [k][d ^ ((k&7)<<3)], V stored transposed [d][k ^ ((d&7)<<3)].
  __shared__ __align__(16) unsigned short Khi[KB * DIM];
  __shared__ __align__(16) unsigned short Klo[KB * DIM];
  __shared__ __align__(16) unsigned short Vt[DIM * KB];
  // P per wave: [q'][k ^ ((q'&7)<<3)]
  __shared__ __align__(16) unsigned short Pl[NW][16 * 64];
  __shared__ unsigned long long Mrow[QB];

  const int tid = threadIdx.x;
  const int w = tid >> 6;
  const int l = tid & 63;
  const int lr = l & 15;
  const int lh = l >> 4;
  const int b = blockIdx.x >> 5;
  const int qt = blockIdx.x & 31;
  const int qbase = qt * QB;
  const int isU8 = *flagp;

  // ---- Q fragments (hi/lo split) in registers ----
  bf16x8 qh[2], ql[2];
  {
    const float* qr = qp + ((size_t)b * LQ + qbase + 16 * w + lr) * DIM;
#pragma unroll
    for (int s = 0; s < 2; ++s) {
#pragma unroll
      for (int j2 = 0; j2 < 2; ++j2) {
        float4 x = *(const float4*)(qr + s * 32 + lh * 8 + j2 * 4);
#pragma unroll
        for (int j = 0; j < 4; ++j) {
          float xv = (&x.x)[j];
          unsigned short h = f2bf(xv);
          qh[s][j2 * 4 + j] = (short)h;
          ql[s][j2 * 4 + j] = (short)f2bf(xv - bf2f(h));
        }
      }
    }
  }

  f32x4 acc_o[4];
#pragma unroll
  for (int g = 0; g < 4; ++g) acc_o[g] = (f32x4){0.f, 0.f, 0.f, 0.f};
  float den[4] = {0.f, 0.f, 0.f, 0.f};

  for (int kt = 0; kt < LK / KB; ++kt) {
    const int kbase = kt * KB;
    __syncthreads();
    // ---- stage K (hi/lo, swizzled) ----
    {
      const float* kg = kp + ((size_t)b * LK + kbase) * DIM;
#pragma unroll
      for (int i = 0; i < 4; ++i) {
        int idx = tid + BLOCK * i;
        int row = idx >> 4;
        int d0 = (idx & 15) * 4;
        float4 kf = *(const float4*)(kg + row * DIM + d0);
        u16x4 khv, klv;
#pragma unroll
        for (int j = 0; j < 4; ++j) {
          float kx = (&kf.x)[j];
          unsigned short h = f2bf(kx);
          khv[j] = h;
          klv[j] = f2bf(kx - bf2f(h));
        }
        int csw = d0 ^ ((row & 7) << 3);
        *(u16x4*)&Khi[row * DIM + csw] = khv;
        *(u16x4*)&Klo[row * DIM + csw] = klv;
      }
    }
    // ---- stage V transposed via 4x4 in-register transpose ----
    {
      const float* vg = vp + ((size_t)b * LK + kbase) * DIM;
      const int kq = tid >> 4;   // k-quad: rows kq*4..+3
      const int dq = tid & 15;   // d-quad: cols dq*4..+3
      unsigned short tmp[4][4];
#pragma unroll
      for (int j = 0; j < 4; ++j) {
        float4 vf = *(const float4*)(vg + (kq * 4 + j) * DIM + dq * 4);
#pragma unroll
        for (int i2 = 0; i2 < 4; ++i2) tmp[j][i2] = f2bf((&vf.x)[i2]);
      }
#pragma unroll
      for (int j2 = 0; j2 < 4; ++j2) {
        u16x4 od;
        od[0] = tmp[0][j2];
        od[1] = tmp[1][j2];
        od[2] = tmp[2][j2];
        od[3] = tmp[3][j2];
        int d = dq * 4 + j2;
        *(u16x4*)&Vt[d * KB + ((kq * 4) ^ ((d & 7) << 3))] = od;
      }
    }
    // ---- stage mask tile as 64 row-bitmasks ----
    if (!isU8) {
      uint32_t mv[16];
#pragma unroll
      for (int rr = 0; rr < 16; ++rr)
        mv[rr] = maskp[((size_t)b * LQ + qbase + 16 * w + rr) * LK + kbase + l];
#pragma unroll
      for (int rr = 0; rr < 16; ++rr) {
        unsigned long long bits = __ballot(mv[rr] != 0);
        if (l == 0) Mrow[16 * w + rr] = bits;
      }
    } else {
      const uint8_t* m8 = (const uint8_t*)maskp;
      uint8_t mv[16];
#pragma unroll
      for (int rr = 0; rr < 16; ++rr)
        mv[rr] = m8[((size_t)b * LQ + qbase + 16 * w + rr) * LK + kbase + l];
#pragma unroll
      for (int rr = 0; rr < 16; ++rr) {
        unsigned long long bits = __ballot(mv[rr] != 0);
        if (l == 0) Mrow[16 * w + rr] = bits;
      }
    }
    __syncthreads();

    // ---- QK^T: S = Qhi*Khi + Qhi*Klo + Qlo*Khi ----
    f32x4 acc_s[4];
#pragma unroll
    for (int f = 0; f < 4; ++f) acc_s[f] = (f32x4){0.f, 0.f, 0.f, 0.f};
#pragma unroll
    for (int f = 0; f < 4; ++f) {
      const int krow = f * 16 + lr;
#pragma unroll
      for (int s = 0; s < 2; ++s) {
        int csw = (s * 32 + lh * 8) ^ ((krow & 7) << 3);
        bf16x8 kh = *(const bf16x8*)&Khi[krow * DIM + csw];
        bf16x8 kl = *(const bf16x8*)&Klo[krow * DIM + csw];
        acc_s[f] = __builtin_amdgcn_mfma_f32_16x16x32_bf16(qh[s], kh, acc_s[f], 0, 0, 0);
        acc_s[f] = __builtin_amdgcn_mfma_f32_16x16x32_bf16(ql[s], kh, acc_s[f], 0, 0, 0);
        acc_s[f] = __builtin_amdgcn_mfma_f32_16x16x32_bf16(qh[s], kl, acc_s[f], 0, 0, 0);
      }
    }

    // ---- mask + exp + P (bf16) to LDS; accumulate denominator ----
    unsigned long long mrows[4];
#pragma unroll
    for (int r = 0; r < 4; ++r) mrows[r] = Mrow[16 * w + lh * 4 + r];
#pragma unroll
    for (int f = 0; f < 4; ++f) {
#pragma unroll
      for (int r = 0; r < 4; ++r) {
        int kc = f * 16 + lr;
        float e = ((mrows[r] >> kc) & 1ull) ? 1.0f
                                            : __expf(acc_s[f][r] * SCALE);
        den[r] += e;
        int qrow = lh * 4 + r;
        Pl[w][qrow * 64 + (kc ^ ((qrow & 7) << 3))] = f2bf(e);
      }
    }

    // ---- PV: O += P * V ----
    bf16x8 pa[2], vbf[2][4];
#pragma unroll
    for (int s2 = 0; s2 < 2; ++s2) {
      pa[s2] = *(const bf16x8*)
          &Pl[w][lr * 64 + ((s2 * 32 + lh * 8) ^ ((lr & 7) << 3))];
#pragma unroll
      for (int g = 0; g < 4; ++g) {
        int d = g * 16 + lr;
        vbf[s2][g] = *(const bf16x8*)
            &Vt[d * KB + ((s2 * 32 + lh * 8) ^ ((d & 7) << 3))];
      }
    }
#pragma unroll
    for (int s2 = 0; s2 < 2; ++s2) {
#pragma unroll
      for (int g = 0; g < 4; ++g) {
        acc_o[g] = __builtin_amdgcn_mfma_f32_16x16x32_bf16(pa[s2], vbf[s2][g],
                                                           acc_o[g], 0, 0, 0);
      }
    }
  }

  // ---- normalize and write ----
#pragma unroll
  for (int r = 0; r < 4; ++r) {
    den[r] += __shfl_xor(den[r], 1);
    den[r] += __shfl_xor(den[r], 2);
    den[r] += __shfl_xor(den[r], 4);
    den[r] += __shfl_xor(den[r], 8);
    den[r] = 1.0f / den[r];
  }
  float* ob = out + ((size_t)b * LQ + qbase + 16 * w) * DIM;
#pragma unroll
  for (int g = 0; g < 4; ++g) {
#pragma unroll
    for (int r = 0; r < 4; ++r) {
      ob[(lh * 4 + r) * DIM + g * 16 + lr] = acc_o[g][r] * den[r];
    }
  }
}

}  // namespace

extern "C" void kernel_launch(void* const* d_in, const int* in_sizes, int n_in,
                              void* d_out, int out_size, void* d_ws,
                              size_t ws_size, hipStream_t stream) {
  const float* q = (const float*)d_in[0];
  const float* k = (const float*)d_in[1];
  const float* v = (const float*)d_in[2];
  const uint32_t* mask = (const uint32_t*)d_in[3];
  float* out = (float*)d_out;
  int* flag = (int*)d_ws;

  detect_mask_dtype<<<1, 256, 0, stream>>>(mask, flag);
  attn_mfma<<<dim3(BATCH * (LQ / QB)), BLOCK, 0, stream>>>(q, k, v, mask, flag,
                                                           out);
}